// Round 1
// baseline (857.290 us; speedup 1.0000x reference)
//
#include <hip/hip_runtime.h>
#include <hip/hip_bf16.h>
#include <hip/hip_fp16.h>

// T=5, B=4, M=4096, N=16384, C=128, G=1024, H=4, K=16. fp32 in/out.

typedef __bf16 v8bf __attribute__((ext_vector_type(8)));
typedef float  v4f  __attribute__((ext_vector_type(4)));

__device__ __forceinline__ float lrelu(float x) { return fmaxf(x, 0.2f * x); }

__device__ __forceinline__ unsigned short f2bf(float x) {
  __hip_bfloat16 h = __float2bfloat16(x);
  return __builtin_bit_cast(unsigned short, h);
}
__device__ __forceinline__ float bf2f(unsigned short u) {
  unsigned int t = ((unsigned int)u) << 16;
  return __builtin_bit_cast(float, t);
}

#define GLOAD_LDS16(gp, lp)                                                   \
  __builtin_amdgcn_global_load_lds(                                           \
      (const __attribute__((address_space(1))) void*)(gp),                    \
      (__attribute__((address_space(3))) void*)(lp), 16, 0, 0)

// raw barrier (no vmcnt drain) + IR-level memory fence
#define RBAR() do { __builtin_amdgcn_s_barrier(); asm volatile("" ::: "memory"); } while (0)
// LDS-ordered barrier: drains lgkm only (keeps global_load_lds prefetch in flight)
#define LBAR() do { asm volatile("s_waitcnt lgkmcnt(0)" ::: "memory");         \
                    __builtin_amdgcn_s_barrier();                              \
                    asm volatile("" ::: "memory"); } while (0)

// ---------------------------------------------------------------------------
// Unified NT bf16 MFMA GEMM (MLP + projections), triple-buffered pipeline:
// one raw barrier per k-step, counted vmcnt(4) (T3+T4), XOR-swizzled LDS (T2):
// source col-block s^((row>>1)&3) pre-swizzled on the global address (LDS dest
// stays linear for global_load_lds), same XOR on ds_read -> 2-way conflicts.
// EP 1: mlp1:  out bf16 = lrelu(acc + aux[col]); ldc
// EP 2: mlp2:  column mean over 128-row tile -> atomicAdd(outv + (m0>>12)*1024 + col)
// EP 3: xl/xr: out half = acc; ldc
// ---------------------------------------------------------------------------
template<int EP>
__global__ __launch_bounds__(256, 2)
void nt_mfma(const unsigned short* __restrict__ A, const unsigned short* __restrict__ B,
             const float* __restrict__ aux, void* __restrict__ outv, int K, int ldc)
{
  __shared__ __align__(16) unsigned short smem[3 * 8192];  // 3 x (A 4096 + B 4096)
  const int tid = threadIdx.x;
  const int l = tid & 63;
  const int w = tid >> 6;
  const int wm = w & 1, wn = w >> 1;
  const int m0 = blockIdx.y << 7, n0 = blockIdx.x << 7;
  const int fr = l & 15, quad = l >> 4;
  const int kt = K >> 5;
  const int xq4 = quad ^ ((fr >> 1) & 3);           // read-side swizzle slot

  const int r0 = tid >> 2;
  const int sw = (tid & 3) ^ ((tid >> 3) & 3);      // source-side swizzle slot
  const unsigned short* Aa = A + (size_t)(m0 + r0) * K + sw * 8;
  const unsigned short* Ab = Aa + (size_t)64 * K;
  const unsigned short* Ba = B + (size_t)(n0 + r0) * K + sw * 8;
  const unsigned short* Bb = Ba + (size_t)64 * K;

  auto stage = [&](int bi, int ks) {
    unsigned short* As = smem + bi * 8192;
    unsigned short* Bs = As + 4096;
    GLOAD_LDS16(Aa + ks * 32, As + tid * 8);
    GLOAD_LDS16(Ab + ks * 32, As + (tid + 256) * 8);
    GLOAD_LDS16(Ba + ks * 32, Bs + tid * 8);
    GLOAD_LDS16(Bb + ks * 32, Bs + (tid + 256) * 8);
  };

  v4f acc[4][4];
#pragma unroll
  for (int i = 0; i < 4; ++i)
#pragma unroll
    for (int j = 0; j < 4; ++j) acc[i][j] = (v4f){0.f, 0.f, 0.f, 0.f};

  stage(0, 0);
  if (kt > 1) stage(1, 1);
  int cur = 0, pend = (kt > 1) ? 2 : 1, sn = 2;

  for (int ks = 0; ks < kt; ++ks) {
    if (pend == 2) asm volatile("s_waitcnt vmcnt(4)" ::: "memory");
    else           asm volatile("s_waitcnt vmcnt(0)" ::: "memory");
    RBAR();
    int nb = cur + 2; if (nb >= 3) nb -= 3;
    if (sn < kt) { stage(nb, sn); ++sn; } else { --pend; }
    const unsigned short* As = smem + cur * 8192;
    const unsigned short* Bs = As + 4096;
    v8bf af[4], bfr[4];
#pragma unroll
    for (int i = 0; i < 4; ++i)
      af[i] = *(const v8bf*)(As + (wm * 64 + i * 16 + fr) * 32 + xq4 * 8);
#pragma unroll
    for (int j = 0; j < 4; ++j)
      bfr[j] = *(const v8bf*)(Bs + (wn * 64 + j * 16 + fr) * 32 + xq4 * 8);
#pragma unroll
    for (int i = 0; i < 4; ++i)
#pragma unroll
      for (int j = 0; j < 4; ++j)
        acc[i][j] = __builtin_amdgcn_mfma_f32_16x16x32_bf16(af[i], bfr[j], acc[i][j], 0, 0, 0);
    __builtin_amdgcn_sched_barrier(0);
    if (++cur == 3) cur = 0;
  }

  if (EP == 1) {
    unsigned short* O = (unsigned short*)outv;
#pragma unroll
    for (int j = 0; j < 4; ++j) {
      int col = n0 + wn * 64 + j * 16 + fr;
      float bias = aux[col];
#pragma unroll
      for (int i = 0; i < 4; ++i) {
        int row = m0 + wm * 64 + i * 16 + quad * 4;
#pragma unroll
        for (int r = 0; r < 4; ++r)
          O[(size_t)(row + r) * ldc + col] = f2bf(lrelu(acc[i][j][r] + bias));
      }
    }
  } else if (EP == 2) {
    __syncthreads();
    float* red = (float*)smem;
#pragma unroll
    for (int j = 0; j < 4; ++j) {
      int lcol = wn * 64 + j * 16 + fr;
      float bias = aux[n0 + lcol];
      float s = 0.f;
#pragma unroll
      for (int i = 0; i < 4; ++i)
#pragma unroll
        for (int r = 0; r < 4; ++r) s += lrelu(acc[i][j][r] + bias);
      s += __shfl_xor(s, 16);
      s += __shfl_xor(s, 32);
      if (quad == 0) red[w * 128 + lcol] = s;
    }
    __syncthreads();
    if (tid < 128) {
      float s = (tid < 64) ? red[0 * 128 + tid] + red[1 * 128 + tid]
                           : red[2 * 128 + tid] + red[3 * 128 + tid];
      atomicAdd((float*)outv + ((m0 >> 12) << 10) + n0 + tid, s * (1.0f / 4096.0f));
    }
  } else {  // EP == 3: half store
    __half* O = (__half*)outv;
#pragma unroll
    for (int j = 0; j < 4; ++j) {
      int col = n0 + wn * 64 + j * 16 + fr;
#pragma unroll
      for (int i = 0; i < 4; ++i) {
        int row = m0 + wm * 64 + i * 16 + quad * 4;
#pragma unroll
        for (int r = 0; r < 4; ++r)
          O[(size_t)(row + r) * ldc + col] = __float2half(acc[i][j][r]);
      }
    }
  }
}

// ---------------------------------------------------------------------------
// knn_fused: dist GEMM + exact per-row top-16, S never materialized.
// Same T2+T3+T4 pipeline as nt_mfma: triple-buffered LDS, one raw barrier per
// k-step, counted vmcnt(4), XOR swizzle. 12 k-steps/col-tile == 0 mod 3, so
// the buffer phase is identical at every col-tile start. Selection uses
// lgkm-only barriers so the next col-tile's 2 prefetched k-steps stay in
// flight across the selection phase (the compiler's wait for xs drains at
// scan start at worst - the prefetch got ~2 k-steps + selection to land).
// ---------------------------------------------------------------------------
__global__ __launch_bounds__(256, 2)
void knn_fused(const unsigned short* __restrict__ ylay,
               const unsigned short* __restrict__ xlay,
               const float* __restrict__ xsq, int* __restrict__ nbrOut)
{
  __shared__ __align__(16) unsigned short smem[3 * 8192];
  __shared__ float candV[128 * 24];
  __shared__ int   candI[128 * 24];
  __shared__ float tauS[128];
  __shared__ int   cntS[128];
  __shared__ int   flagS;

  const int tid = threadIdx.x;
  const int l = tid & 63;
  const int w = tid >> 6;
  const int wm = w & 1, wn = w >> 1;
  const int pair = blockIdx.x >> 5;
  const int rb = blockIdx.x & 31;
  const int f = pair >> 2, b = pair & 3;
  const int m0 = rb << 7;
  const int fr = l & 15, quad = l >> 4;
  const int xq4 = quad ^ ((fr >> 1) & 3);

  const unsigned short* A = ylay + (size_t)b * 4096 * 384;
  const unsigned short* B = xlay + ((size_t)f * 16384 + (size_t)b * 4096) * 384;
  const float* xq = xsq + f * 16384 + b * 4096;

  const int r0 = tid >> 2;
  const int sw = (tid & 3) ^ ((tid >> 3) & 3);
  const unsigned short* Aa = A + (size_t)(m0 + r0) * 384 + sw * 8;
  const unsigned short* Ab = Aa + 64 * 384;
  const unsigned short* Brow = B + (size_t)r0 * 384 + sw * 8;

  auto stage = [&](int bi, int ct, int ks) {
    unsigned short* As = smem + bi * 8192;
    unsigned short* Bs = As + 4096;
    const unsigned short* Bt = Brow + ct * 49152 + ks * 32;
    GLOAD_LDS16(Aa + ks * 32, As + tid * 8);
    GLOAD_LDS16(Ab + ks * 32, As + (tid + 256) * 8);
    GLOAD_LDS16(Bt, Bs + tid * 8);
    GLOAD_LDS16(Bt + 64 * 384, Bs + (tid + 256) * 8);
  };

  // owner-thread (tid<128) register top-16 for local row = tid
  float tv[16];
  int   ti[16];
#pragma unroll
  for (int k = 0; k < 16; ++k) { tv[k] = -3.0e38f; ti[k] = k; }
  float ownMin = -3.0e38f;
  int ownMinPos = 0;
  if (tid < 128) { tauS[tid] = -3.0e38f; cntS[tid] = 0; }
  if (tid == 0) flagS = 0;

  // lane tau cache for its 16 rows (i,r)
  float tc[16];
#pragma unroll
  for (int i = 0; i < 16; ++i) tc[i] = -3.0e38f;

  // pipeline prologue: stage steps (0,0) and (0,1)
  stage(0, 0, 0);
  stage(1, 0, 1);
  int cur = 0, pend = 2, sct = 0, sks = 2;

  LBAR();  // init visible; does NOT drain the prefetch

  for (int ct = 0; ct < 32; ++ct) {
    const int n0 = ct << 7;
    float xs[4];
#pragma unroll
    for (int j = 0; j < 4; ++j) xs[j] = xq[n0 + wn * 64 + j * 16 + fr];

    v4f acc[4][4];
#pragma unroll
    for (int i = 0; i < 4; ++i)
#pragma unroll
      for (int j = 0; j < 4; ++j) acc[i][j] = (v4f){0.f, 0.f, 0.f, 0.f};

    for (int ks = 0; ks < 12; ++ks) {
      if (pend == 2) asm volatile("s_waitcnt vmcnt(4)" ::: "memory");
      else           asm volatile("s_waitcnt vmcnt(0)" ::: "memory");
      RBAR();
      int nb = cur + 2; if (nb >= 3) nb -= 3;
      if (sct < 32) {
        stage(nb, sct, sks);
        if (++sks == 12) { sks = 0; ++sct; }
      } else { --pend; }
      const unsigned short* As = smem + cur * 8192;
      const unsigned short* Bs = As + 4096;
      v8bf af[4], bfr[4];
#pragma unroll
      for (int i = 0; i < 4; ++i)
        af[i] = *(const v8bf*)(As + (wm * 64 + i * 16 + fr) * 32 + xq4 * 8);
#pragma unroll
      for (int j = 0; j < 4; ++j)
        bfr[j] = *(const v8bf*)(Bs + (wn * 64 + j * 16 + fr) * 32 + xq4 * 8);
#pragma unroll
      for (int i = 0; i < 4; ++i)
#pragma unroll
        for (int j = 0; j < 4; ++j)
          acc[i][j] = __builtin_amdgcn_mfma_f32_16x16x32_bf16(af[i], bfr[j], acc[i][j], 0, 0, 0);
      __builtin_amdgcn_sched_barrier(0);
      if (++cur == 3) cur = 0;
    }

    unsigned long long pushed = 0ull;
    for (;;) {
      // scan: rare candidates -> LDS buffer
#pragma unroll
      for (int i = 0; i < 4; ++i)
#pragma unroll
        for (int r = 0; r < 4; ++r) {
          const int lrow = wm * 64 + i * 16 + quad * 4 + r;
          const float tau = tc[i * 4 + r];
#pragma unroll
          for (int j = 0; j < 4; ++j) {
            const int bit = i * 16 + j * 4 + r;
            float v = 2.f * acc[i][j][r] - xs[j];
            if (v > tau && !((pushed >> bit) & 1ull)) {
              int pos = atomicAdd(&cntS[lrow], 1);
              if (pos < 24) {
                candV[lrow * 24 + pos] = v;
                candI[lrow * 24 + pos] = n0 + wn * 64 + j * 16 + fr;
                pushed |= (1ull << bit);
              }
            }
          }
        }
      LBAR();
      // owner merge
      if (tid < 128) {
        int c = cntS[tid];
        int cc = c < 24 ? c : 24;
        for (int q = 0; q < cc; ++q) {
          float v = candV[tid * 24 + q];
          if (v > ownMin) {
            tv[ownMinPos] = v;
            ti[ownMinPos] = candI[tid * 24 + q];
            ownMin = tv[0]; ownMinPos = 0;
#pragma unroll
            for (int k = 1; k < 16; ++k)
              if (tv[k] < ownMin) { ownMin = tv[k]; ownMinPos = k; }
          }
        }
        tauS[tid] = ownMin;
        if (c > 24) flagS = 1;
        cntS[tid] = 0;
      }
      LBAR();
#pragma unroll
      for (int i = 0; i < 4; ++i)
#pragma unroll
        for (int r = 0; r < 4; ++r)
          tc[i * 4 + r] = tauS[wm * 64 + i * 16 + quad * 4 + r];
      int ov = flagS;
      LBAR();
      if (tid == 0) flagS = 0;
      if (!ov) break;
    }
  }

  if (tid < 128) {
    const int base = b * 4096;
    int* outp = nbrOut + ((size_t)(f * 16384 + b * 4096) + m0 + tid) * 16;
#pragma unroll
    for (int k = 0; k < 16; ++k) outp[k] = base + ti[k];
  }
}

// ---------------------------------------------------------------------------
// convert_inputs (unchanged)
// ---------------------------------------------------------------------------
__global__ __launch_bounds__(256)
void convert_inputs(const float* __restrict__ seq, unsigned short* __restrict__ seqbf,
                    unsigned short* __restrict__ ylay, unsigned short* __restrict__ xlay,
                    float* __restrict__ xsq)
{
  const int tid = threadIdx.x;
  const int row = blockIdx.x * 8 + (tid >> 5);
  const int c4 = tid & 31;
  float4 v = *(const float4*)(seq + (size_t)row * 128 + c4 * 4);
  ushort4 hi, lo;
  hi.x = f2bf(v.x); lo.x = f2bf(v.x - bf2f(hi.x));
  hi.y = f2bf(v.y); lo.y = f2bf(v.y - bf2f(hi.y));
  hi.z = f2bf(v.z); lo.z = f2bf(v.z - bf2f(hi.z));
  hi.w = f2bf(v.w); lo.w = f2bf(v.w - bf2f(hi.w));
  *(ushort4*)(seqbf + (size_t)row * 128 + c4 * 4) = hi;
  float ss = v.x * v.x + v.y * v.y + v.z * v.z + v.w * v.w;
#pragma unroll
  for (int off = 16; off; off >>= 1) ss += __shfl_xor(ss, off);
  if (row < 65536) {
    unsigned short* p = xlay + (size_t)row * 384 + c4 * 4;
    *(ushort4*)(p) = hi; *(ushort4*)(p + 128) = lo; *(ushort4*)(p + 256) = hi;
    if (c4 == 0) xsq[row] = ss;
  } else {
    unsigned short* p = ylay + (size_t)(row - 65536) * 384 + c4 * 4;
    *(ushort4*)(p) = hi; *(ushort4*)(p + 128) = hi; *(ushort4*)(p + 256) = lo;
  }
}

// ---------------------------------------------------------------------------
// convert_weights (unchanged)
// ---------------------------------------------------------------------------
__global__ __launch_bounds__(256)
void convert_weights(const float* __restrict__ W1, const float* __restrict__ W2,
                     const float* __restrict__ Wl, const float* __restrict__ Wr,
                     const float* __restrict__ aw,
                     unsigned short* __restrict__ W1t, unsigned short* __restrict__ W2t,
                     unsigned short* __restrict__ Wlv, unsigned short* __restrict__ Wrv,
                     __half* __restrict__ awh)
{
  int idx = blockIdx.x * 256 + threadIdx.x;
  if (idx < 16384) {
    int n = idx >> 7, k = idx & 127;
    W1t[idx] = f2bf(W1[k * 128 + n]);
  } else if (idx < 147456) {
    int i = idx - 16384; int n = i >> 7, k = i & 127;
    W2t[i] = f2bf(W2[k * 1024 + n]);
  } else if (idx < 344064) {
    int i = idx - 147456; int n = i / 384, k = i % 384;
    int s = k >> 7, kk = k & 127;
    float wv = Wl[kk * 512 + n];
    unsigned short h = f2bf(wv);
    Wlv[i] = (s == 1) ? f2bf(wv - bf2f(h)) : h;
  } else if (idx < 540672) {
    int i = idx - 344064; int n = i / 384, k = i % 384;
    int s = k >> 7, kk = k & 127;
    float wv = Wr[kk * 512 + n];
    unsigned short h = f2bf(wv);
    Wrv[i] = (s == 2) ? f2bf(wv - bf2f(h)) : h;
  } else if (idx < 541184) {
    int i = idx - 540672;
    awh[i] = __float2half(aw[i]);
  }
}

// ---------------------------------------------------------------------------
// Temporal attention weights (unchanged)
// ---------------------------------------------------------------------------
__global__ __launch_bounds__(1024)
void temporal_attn(const float* __restrict__ gfea, float* __restrict__ attnw)
{
  const int tid = threadIdx.x;
  const int w = tid >> 6, l = tid & 63;
  const int b = w >> 2, i = w & 3;
  const float* q  = gfea + (16 + b) * 1024;
  const float* kv = gfea + (i * 4 + b) * 1024;
  float p = 0.f;
  for (int g = l; g < 1024; g += 64) p += q[g] * kv[g];
#pragma unroll
  for (int off = 32; off; off >>= 1) p += __shfl_xor(p, off);
  __shared__ float sc[16];
  if (l == 0) sc[w] = p * 0.03125f;
  __syncthreads();
  if (tid < 4) {
    float v0 = sc[tid * 4 + 0], v1 = sc[tid * 4 + 1];
    float v2 = sc[tid * 4 + 2], v3 = sc[tid * 4 + 3];
    float mm = fmaxf(fmaxf(v0, v1), fmaxf(v2, v3));
    v0 = __expf(v0 - mm); v1 = __expf(v1 - mm);
    v2 = __expf(v2 - mm); v3 = __expf(v3 - mm);
    float inv = 1.f / (v0 + v1 + v2 + v3);
    attnw[tid * 4 + 0] = v0 * inv;
    attnw[tid * 4 + 1] = v1 * inv;
    attnw[tid * 4 + 2] = v2 * inv;
    attnw[tid * 4 + 3] = v3 * inv;
  }
}

// ---------------------------------------------------------------------------
// gat6 (chunked single-fetch) + XCD-aware swizzle (unchanged)
// ---------------------------------------------------------------------------
__global__ __launch_bounds__(256)
void gat6(const __half* __restrict__ xlh, const __half* __restrict__ xrh,
          const int* __restrict__ nbr, const __half* __restrict__ awh,
          const float* __restrict__ attnw, float* __restrict__ wgt4)
{
  const int tid = threadIdx.x;
  const int l = tid & 63;
  const int blk = blockIdx.x;
  const int r8 = blk & 7;
  const int b = r8 >> 1;                      // XCD pair -> batch
  const int g = ((blk >> 3) << 1) | (r8 & 1); // [0, 4096)
  const int f = g >> 10;
  const int n4 = g & 1023;
  const int qid = f * 16384 + b * 4096 + n4 * 4 + (tid >> 6);
  const int h = l >> 4, cp = l & 15;
  const float fw = attnw[b * 4 + f] * 0.25f;

  const int jl = nbr[qid * 16 + (l & 15)];
  const __half* xbase = xlh + h * 128 + cp * 8;

  const __half2* xrp = (const __half2*)(xrh + (size_t)qid * 512 + h * 128 + cp * 8);
  float2 xr0 = __half22float2(xrp[0]), xr1 = __half22float2(xrp[1]);
  float2 xr2 = __half22float2(xrp[2]), xr3 = __half22float2(xrp[3]);
  const __half2* awp = (const __half2*)(awh + h * 128 + cp * 8);
  float2 aw0 = __half22float2(awp[0]), aw1 = __half22float2(awp[1]);
  float2 aw2 = __half22float2(awp[2]), aw3 = __half22float2(awp[3]);

  float m = -3.0e38f, s = 0.f;
  float o[8];
#pragma unroll
  for (int c = 0; c < 8; ++c) o[c] = 0.f;

  for (int ch = 0; ch < 2; ++ch) {
    float4 xv[8];
#pragma unroll
    for (int k = 0; k < 8; ++k) {
      int j = __shfl(jl, ch * 8 + k);
      xv[k] = *(const float4*)(xbase + (size_t)j * 512);
    }
    float e[8];
#pragma unroll
    for (int k = 0; k < 8; ++k) {
      const __half2* hp = (const __half2*)&xv[k];
      float2 x0 = __half22float2(hp[0]), x1 = __half22float2(hp[1]);
      float2 x2 = __half22float2(hp[2]), x3 = __half22float2(hp[3]);
      float p = 0.f;
      p += lrelu(x0.x + xr0.x) * aw0.x + lrelu(x0.y + xr0.y) * aw0.y;
      p += lrelu(x1.x + xr1.x) * aw1.x + lrelu(x1.y + xr1.y) * aw1.y;
      p += lrelu(x2.x + xr2.x) * aw2.x + lrelu(x2.y + xr2.y) * aw2.y;
      p += lrelu(x3.x + xr3.x) * aw3.x + lrelu(x3.y + xr3.y) * aw3.y;
      p += __shfl_xor(p, 1);
      p += __shfl_xor(p, 2);
      p += __shfl_xor(p, 4);
      p += __shfl_xor(p, 8);
      e[k] = p;
    }
    float mc = e[0];
#pragma unroll
    for (int k = 1; k < 8; ++k) mc = fmaxf(mc, e[k]);
    float mn = fmaxf(m, mc);
    float cr = __expf(m - mn);
    s *= cr;
#pragma unroll
    for (int c = 0; c < 8; ++c) o[c] *= cr;
#pragma unroll
    for (int k = 0; k < 8; ++k) {
      float a = __expf(e[k] - mn);
      s += a;
      const __half2* hp = (const __half2*)&xv[k];
      float2 f0 = __half22float2(hp[0]);
      float2 f1 = __half22float2(hp[1]);
      float2 f2 = __half22float2(hp[2]);
      float2 f3 = __half22float2(hp[3]);
      o[0] += a * f0.x; o[1] += a * f0.y;
      o[2] += a * f1.x; o[3] += a * f1.y;
      o[4] += a * f2.x; o[5] += a * f2.y;
      o[6] += a * f3.x; o[7] += a * f3.y;
    }
    m = mn;
  }

  const float sc = fw / s;
#pragma unroll
  for (int c = 0; c < 8; ++c) {
    float t = o[c] * sc;
    t += __shfl_xor(t, 16);
    t += __shfl_xor(t, 32);
    o[c] = t;
  }
  if (l < 16) {
    float* wp = wgt4 + (size_t)qid * 128 + l * 8;
    *(float4*)(wp)     = make_float4(o[0], o[1], o[2], o[3]);
    *(float4*)(wp + 4) = make_float4(o[4], o[5], o[6], o[7]);
  }
}

// ---------------------------------------------------------------------------
// finalize (unchanged)
// ---------------------------------------------------------------------------
__global__ __launch_bounds__(256)
void finalize2(const float* __restrict__ last, const float* __restrict__ wgt4,
               float* __restrict__ out)
{
  int idx = blockIdx.x * 256 + threadIdx.x;
  int n = idx >> 6, q = idx & 63;
  float4 v;
  if (q < 32) {
    v = *(const float4*)(last + (size_t)n * 128 + 4 * q);
  } else {
    int c = (q - 32) * 4;
    v = make_float4(0.f, 0.f, 0.f, 0.f);
#pragma unroll
    for (int f = 0; f < 4; ++f) {
      float4 t = *(const float4*)(wgt4 + ((size_t)f * 16384 + n) * 128 + c);
      v.x += t.x; v.y += t.y; v.z += t.z; v.w += t.w;
    }
  }
  *(float4*)(out + (size_t)n * 256 + 4 * q) = v;
}

extern "C" void kernel_launch(void* const* d_in, const int* in_sizes, int n_in,
                              void* d_out, int out_size, void* d_ws, size_t ws_size,
                              hipStream_t stream)
{
  (void)in_sizes; (void)n_in; (void)out_size; (void)ws_size;
  const float* seq = (const float*)d_in[0];
  const float* W1  = (const float*)d_in[1];
  const float* b1  = (const float*)d_in[2];
  const float* W2  = (const float*)d_in[3];
  const float* b2  = (const float*)d_in[4];
  const float* Wl  = (const float*)d_in[5];
  const float* Wr  = (const float*)d_in[6];
  const float* aw  = (const float*)d_in[7];
  float* out = (float*)d_out;

  // workspace layout (float offsets); ~178 MiB total
  float* ws = (float*)d_ws;
  __half* xrh          = (__half*)ws;                          // 65536x512 half (32 MB region)
  unsigned short* seqbf = (unsigned short*)(ws + 16777216);    // 10,485,760 us
  unsigned short* h1bf  = (unsigned short*)(ws + 22020096);    // 10,485,760 us
  __half* xlh           = (__half*)(ws + 22020096);            // alias after mlp2: 16384x512 half
  unsigned short* ylay  = (unsigned short*)(ws + 27262976);    // 6,291,456 us
  unsigned short* xlay  = (unsigned short*)(ws + 30408704);    // 25,165,824 us
  float* wgt4           = ws + 30408704;                       // alias after xr gemm: 8,388,608 f
  float* gfea           = ws + 42991616;                       // 20,480
  float* attn           = gfea + 20480;                        // 16
  float* xsq            = attn + 16;                           // 65,536
  int*   nbr            = (int*)(xsq + 65536);                 // 1,048,576 ints
  unsigned short* W1t   = (unsigned short*)(nbr + 1048576);    // 16,384 us
  unsigned short* W2t   = W1t + 16384;                         // 131,072 us
  unsigned short* Wlv   = W2t + 131072;                        // 196,608 us
  unsigned short* Wrv   = Wlv + 196608;                        // 196,608 us
  __half* awh           = (__half*)(Wrv + 196608);             // 512 halves

  (void)hipMemsetAsync(gfea, 0, 20480 * sizeof(float), stream);

  // conversions
  convert_inputs<<<10240, 256, 0, stream>>>(seq, seqbf, ylay, xlay, xsq);
  convert_weights<<<2114, 256, 0, stream>>>(W1, W2, Wl, Wr, aw, W1t, W2t, Wlv, Wrv, awh);

  // MLP (bf16 MFMA) + temporal attention
  nt_mfma<1><<<dim3(1, 640), 256, 0, stream>>>(seqbf, W1t, b1, h1bf, 128, 128);
  nt_mfma<2><<<dim3(8, 640), 256, 0, stream>>>(h1bf, W2t, b2, gfea, 128, 0);
  temporal_attn<<<1, 1024, 0, stream>>>(gfea, attn);

  // KNN: all 16 pairs fused (dist MFMA + exact top-16), no S buffer
  knn_fused<<<512, 256, 0, stream>>>(ylay, xlay, xsq, nbr);

  // GAT projections (split-bf16 MFMA -> half)
  nt_mfma<3><<<dim3(4, 128), 256, 0, stream>>>(ylay, Wlv, nullptr, xlh, 384, 512);
  nt_mfma<3><<<dim3(4, 512), 256, 0, stream>>>(xlay, Wrv, nullptr, xrh, 384, 512);

  // GAT gather/softmax/aggregate (XCD-swizzled)
  gat6<<<16384, 256, 0, stream>>>(xlh, xrh, nbr, awh, attn, wgt4);

  finalize2<<<4096, 256, 0, stream>>>(seq + (size_t)4 * 16384 * 128, wgt4, out);
}